// Round 1
// baseline (127.386 us; speedup 1.0000x reference)
//
#include <hip/hip_runtime.h>
#include <math.h>

#define BB 32
#define NN 1000
#define CC 81
#define NPAD 1024
#define MAX_INST 100
#define MIN_CONF 0.7f
#define NMS_THRESH 0.3f

__global__ __launch_bounds__(1024) void detection_kernel(
    const float* __restrict__ rois,       // B,N,4
    const float* __restrict__ probs,      // B,N,C
    const float* __restrict__ deltas,     // B,N,C,4
    const float* __restrict__ std_dev,    // 4
    float* __restrict__ out)              // B,MAX_INST,6
{
  const int b = blockIdx.x;
  const int t = threadIdx.x;

  __shared__ float sbox[NPAD][4];
  __shared__ float sscore[NPAD];
  __shared__ int   scls[NPAD];
  __shared__ float skey[NPAD];
  __shared__ short sidx[NPAD];
  __shared__ int   skeep[NPAD];
  __shared__ int   sscan[NPAD];
  __shared__ int   sM;

  // zero this batch's output slab (harness poisons d_out with 0xAA)
  for (int i = t; i < MAX_INST * 6; i += blockDim.x)
    out[(size_t)b * MAX_INST * 6 + i] = 0.0f;
  if (t == 0) sM = 0;

  float key = INFINITY;
  if (t < NN) {
    const int n = t;
    const float* p = probs + (size_t)(b * NN + n) * CC;
    float best = -INFINITY; int bc = 0;
    for (int c = 0; c < CC; ++c) {
      float v = p[c];
      if (v > best) { best = v; bc = c; }   // first-occurrence argmax
    }
    const float* d = deltas + ((size_t)(b * NN + n) * CC + bc) * 4;
    float dy = d[0] * std_dev[0];
    float dx = d[1] * std_dev[1];
    float dh = d[2] * std_dev[2];
    float dw = d[3] * std_dev[3];
    const float* r = rois + (size_t)(b * NN + n) * 4;
    float y1 = r[0], x1 = r[1], y2 = r[2], x2 = r[3];
    float h = y2 - y1, w = x2 - x1;
    float cy = y1 + 0.5f * h + dy * h;
    float cx = x1 + 0.5f * w + dx * w;
    h = h * expf(dh);
    w = w * expf(dw);
    float ny1 = cy - 0.5f * h;
    float nx1 = cx - 0.5f * w;
    float ny2 = ny1 + h;
    float nx2 = nx1 + w;
    ny1 = fminf(fmaxf(ny1, 0.0f), 1.0f);
    nx1 = fminf(fmaxf(nx1, 0.0f), 1.0f);
    ny2 = fminf(fmaxf(ny2, 0.0f), 1.0f);
    nx2 = fminf(fmaxf(nx2, 0.0f), 1.0f);
    sbox[t][0] = ny1; sbox[t][1] = nx1; sbox[t][2] = ny2; sbox[t][3] = nx2;
    sscore[t] = best; scls[t] = bc;
    bool valid = (bc > 0) && (best >= MIN_CONF);
    if (valid) { key = -best; atomicAdd(&sM, 1); }
  }
  skey[t] = key;
  sidx[t] = (short)t;
  __syncthreads();

  // Bitonic sort over 1024 (key asc, original-index tiebreak) == stable argsort
  for (int k = 2; k <= NPAD; k <<= 1) {
    for (int j = k >> 1; j > 0; j >>= 1) {
      int ixj = t ^ j;
      if (ixj > t) {
        float k1 = skey[t], k2 = skey[ixj];
        short i1 = sidx[t], i2 = sidx[ixj];
        bool gt = (k1 > k2) || (k1 == k2 && i1 > i2);
        bool up = ((t & k) == 0);
        if (gt == up) {
          skey[t] = k2; skey[ixj] = k1;
          sidx[t] = i2; sidx[ixj] = i1;
        }
      }
      __syncthreads();
    }
  }

  const int M = sM;   // number of valid entries; they occupy sorted ranks [0, M)
  int oj = sidx[t];
  bool inM = (t < M);
  float by1 = 0.f, bx1 = 0.f, by2 = 0.f, bx2 = 0.f, ms = 0.f;
  int mc = -1;
  if (inM) {
    by1 = sbox[oj][0]; bx1 = sbox[oj][1];
    by2 = sbox[oj][2]; bx2 = sbox[oj][3];
    mc = scls[oj]; ms = sscore[oj];
  }
  float area_j = (by2 - by1) * (bx2 - bx1);
  skeep[t] = inM ? 1 : 0;
  __syncthreads();

  // Sequential NMS over sorted valid entries (M is typically ~10-20)
  for (int i = 0; i < M; ++i) {
    if (skeep[i]) {                       // uniform broadcast read
      int oi = sidx[i];
      float iy1 = sbox[oi][0], ix1 = sbox[oi][1];
      float iy2 = sbox[oi][2], ix2 = sbox[oi][3];
      int ic = scls[oi];
      if (inM && t > i && mc == ic) {
        float area_i = (iy2 - iy1) * (ix2 - ix1);
        float iy = fmaxf(fminf(iy2, by2) - fmaxf(iy1, by1), 0.0f);
        float ix = fmaxf(fminf(ix2, bx2) - fmaxf(ix1, bx1), 0.0f);
        float inter = iy * ix;
        float uni = area_i + area_j - inter;
        float iou = inter / fmaxf(uni, 1e-8f);
        if (iou > NMS_THRESH) skeep[t] = 0;
      }
    }
    __syncthreads();
  }

  // Inclusive scan of keep -> output slot
  sscan[t] = skeep[t];
  __syncthreads();
  for (int off = 1; off < NPAD; off <<= 1) {
    int v = sscan[t];
    if (t >= off) v += sscan[t - off];
    __syncthreads();
    sscan[t] = v;
    __syncthreads();
  }

  if (inM && skeep[t]) {
    int slot = sscan[t] - 1;
    if (slot < MAX_INST) {
      float* o = out + ((size_t)b * MAX_INST + slot) * 6;
      o[0] = by1; o[1] = bx1; o[2] = by2; o[3] = bx2;
      o[4] = (float)mc; o[5] = ms;
    }
  }
}

extern "C" void kernel_launch(void* const* d_in, const int* in_sizes, int n_in,
                              void* d_out, int out_size, void* d_ws, size_t ws_size,
                              hipStream_t stream) {
  const float* rois    = (const float*)d_in[0];
  const float* probs   = (const float*)d_in[1];
  const float* deltas  = (const float*)d_in[2];
  const float* std_dev = (const float*)d_in[3];
  float* out = (float*)d_out;
  detection_kernel<<<BB, 1024, 0, stream>>>(rois, probs, deltas, std_dev, out);
}

// Round 2
// 106.478 us; speedup vs baseline: 1.1964x; 1.1964x over previous
//
#include <hip/hip_runtime.h>
#include <math.h>

#define BB 32
#define NN 1000
#define CC 81
#define MAX_INST 100
#define MIN_CONF 0.7f
#define NMS_THRESH 0.3f
#define MCAP 1024     // >= NN, capacity for valid candidates
#define RCHUNK 192    // suppression-matrix rows per chunk
#define WMAX 16       // 64-bit words per keep row (1024/64)

// ---------------- Kernel A: one wave (64 lanes) per ROI ----------------
// Argmax over 81 classes via coalesced lane loads + shuffle reduce,
// then box decode/clip on lane 0; writes an 8-float record per ROI to ws.
__global__ __launch_bounds__(256) void roi_kernel(
    const float* __restrict__ rois,      // B,N,4
    const float* __restrict__ probs,     // B,N,C
    const float* __restrict__ deltas,    // B,N,C,4
    const float* __restrict__ std_dev,   // 4
    float* __restrict__ rec)             // B*N x 8: y1,x1,y2,x2,score,cls,0,0
{
  int wg = blockIdx.x * 4 + (threadIdx.x >> 6);
  if (wg >= BB * NN) return;
  int lane = threadIdx.x & 63;

  const float* p = probs + (size_t)wg * CC;
  float v = p[lane];              // lanes 0..63 cover classes 0..63
  int   c = lane;
  if (lane + 64 < CC) {           // lanes 0..16 also cover classes 64..80
    float v2 = p[lane + 64];
    if (v2 > v) { v = v2; c = lane + 64; }   // c1 < c2 so ties keep lower class
  }
  // first-occurrence argmax: on ties keep smaller class index
  for (int off = 32; off; off >>= 1) {
    float vo = __shfl_down(v, off);
    int   co = __shfl_down(c, off);
    if (vo > v || (vo == v && co < c)) { v = vo; c = co; }
  }

  if (lane == 0) {
    float4 dd = *(const float4*)(deltas + ((size_t)wg * CC + c) * 4);
    float4 r4 = *(const float4*)(rois + (size_t)wg * 4);
    float dy = dd.x * std_dev[0], dx = dd.y * std_dev[1];
    float dh = dd.z * std_dev[2], dw = dd.w * std_dev[3];
    float h = r4.z - r4.x, w = r4.w - r4.y;
    float cy = r4.x + 0.5f * h + dy * h;
    float cx = r4.y + 0.5f * w + dx * w;
    h *= expf(dh); w *= expf(dw);
    float y1 = cy - 0.5f * h, x1 = cx - 0.5f * w;
    float y2 = y1 + h,        x2 = x1 + w;
    y1 = fminf(fmaxf(y1, 0.f), 1.f); x1 = fminf(fmaxf(x1, 0.f), 1.f);
    y2 = fminf(fmaxf(y2, 0.f), 1.f); x2 = fminf(fmaxf(x2, 0.f), 1.f);
    float4* o = (float4*)(rec + (size_t)wg * 8);
    o[0] = make_float4(y1, x1, y2, x2);
    o[1] = make_float4(v, (float)c, 0.f, 0.f);
  }
}

// ---------------- Kernel B: one block per batch — sort + NMS + compact --------
__global__ __launch_bounds__(1024) void nms_kernel(
    const float* __restrict__ rec,   // B*N x 8
    float* __restrict__ out)         // B,MAX_INST,6
{
  const int b = blockIdx.x, t = threadIdx.x;

  __shared__ float cscore[MCAP];   // compact (append-order) scores
  __shared__ int   cidx[MCAP];     // compact original indices
  __shared__ float sy1[MCAP], sx1[MCAP], sy2[MCAP], sx2[MCAP]; // sorted boxes
  __shared__ int   scls[MCAP];     // sorted classes
  __shared__ unsigned long long rows[RCHUNK][WMAX]; // suppression bits chunk
  __shared__ unsigned long long keepw[WMAX];
  __shared__ int cnt;

  // zero this batch's output slab (d_out is poisoned 0xAA)
  for (int i = t; i < MAX_INST * 6; i += 1024)
    out[(size_t)b * MAX_INST * 6 + i] = 0.0f;
  if (t == 0) cnt = 0;
  __syncthreads();

  // load per-ROI record; append valid ones (order-independent)
  float y1 = 0, x1 = 0, y2 = 0, x2 = 0, score = 0;
  int cls = 0; bool valid = false; int pos = -1;
  if (t < NN) {
    const float4* rr = (const float4*)(rec + ((size_t)b * NN + t) * 8);
    float4 a = rr[0], s = rr[1];
    y1 = a.x; x1 = a.y; y2 = a.z; x2 = a.w;
    score = s.x; cls = (int)s.y;
    valid = (cls > 0) && (score >= MIN_CONF);
    if (valid) pos = atomicAdd(&cnt, 1);
  }
  if (valid) { cscore[pos] = score; cidx[pos] = t; }
  __syncthreads();
  const int M = cnt;
  const int W = (M + 63) >> 6;

  // rank = stable-argsort position: count of (score',idx') strictly ahead
  int r = 0;
  if (valid) {
    for (int j = 0; j < M; ++j) {
      float sj = cscore[j]; int ij = cidx[j];
      if (sj > score || (sj == score && ij < t)) ++r;
    }
    sy1[r] = y1; sx1[r] = x1; sy2[r] = y2; sx2[r] = x2; scls[r] = cls;
  }
  // init keep mask: first M sorted slots are valid
  if (t < WMAX) {
    unsigned long long kw = 0ULL;
    int base = t * 64;
    if (base < M) {
      int nb = M - base;
      kw = (nb >= 64) ? ~0ULL : ((1ULL << nb) - 1ULL);
    }
    keepw[t] = kw;
  }
  __syncthreads();

  // chunked suppression matrix + serial propagation
  const int wv = t >> 6, lane = t & 63;
  for (int c0 = 0; c0 < M; c0 += RCHUNK) {
    int R = min(RCHUNK, M - c0);
    // each wave builds one 64-bit row-word per task via ballot
    for (int task = wv; task < R * W; task += 16) {
      int i = c0 + task / W;
      int w = task % W;
      int j = w * 64 + lane;
      bool cond = false;
      float iy1 = sy1[i], ix1 = sx1[i], iy2 = sy2[i], ix2 = sx2[i]; // broadcast
      int ic = scls[i];
      if (j < M && j > i && scls[j] == ic) {
        float jy1 = sy1[j], jx1 = sx1[j], jy2 = sy2[j], jx2 = sx2[j];
        float ai = (iy2 - iy1) * (ix2 - ix1);
        float aj = (jy2 - jy1) * (jx2 - jx1);
        float iy = fmaxf(fminf(iy2, jy2) - fmaxf(iy1, jy1), 0.f);
        float ix = fmaxf(fminf(ix2, jx2) - fmaxf(ix1, jx1), 0.f);
        float inter = iy * ix;
        float uni = fmaxf(ai + aj - inter, 1e-8f);
        cond = (inter / uni) > NMS_THRESH;
      }
      unsigned long long word = __ballot(cond);
      if (lane == 0) rows[task / W][w] = word;
    }
    __syncthreads();
    // wave 0: strictly-serial keep propagation over this chunk
    if (t < 64) {
      unsigned long long kw = (t < W) ? keepw[t] : 0ULL;
      for (int i = c0; i < c0 + R; ++i) {
        unsigned long long kwi = __shfl((long long)kw, i >> 6); // uniform
        if ((((unsigned long long)kwi) >> (i & 63)) & 1ULL) {
          if (t < W) kw &= ~rows[i - c0][t];
        }
      }
      if (t < W) keepw[t] = kw;
    }
    __syncthreads();
  }

  // slot = popcount of kept entries ahead of me; write row
  if (valid) {
    unsigned long long kwme = keepw[r >> 6];
    if ((kwme >> (r & 63)) & 1ULL) {
      int slot = 0;
      for (int w = 0; w < (r >> 6); ++w) slot += __popcll(keepw[w]);
      slot += __popcll(kwme & ((1ULL << (r & 63)) - 1ULL));
      if (slot < MAX_INST) {
        float* o = out + ((size_t)b * MAX_INST + slot) * 6;
        o[0] = y1; o[1] = x1; o[2] = y2; o[3] = x2;
        o[4] = (float)cls; o[5] = score;
      }
    }
  }
}

extern "C" void kernel_launch(void* const* d_in, const int* in_sizes, int n_in,
                              void* d_out, int out_size, void* d_ws, size_t ws_size,
                              hipStream_t stream) {
  const float* rois    = (const float*)d_in[0];
  const float* probs   = (const float*)d_in[1];
  const float* deltas  = (const float*)d_in[2];
  const float* std_dev = (const float*)d_in[3];
  float* out = (float*)d_out;
  float* rec = (float*)d_ws;   // 32000 * 8 floats = 1 MB

  roi_kernel<<<(BB * NN + 3) / 4, 256, 0, stream>>>(rois, probs, deltas, std_dev, rec);
  nms_kernel<<<BB, 1024, 0, stream>>>(rec, out);
}

// Round 3
// 104.834 us; speedup vs baseline: 1.2151x; 1.0157x over previous
//
#include <hip/hip_runtime.h>
#include <math.h>

#define BB 32
#define NN 1000
#define CC 81
#define MAX_INST 100
#define MIN_CONF 0.7f
#define NMS_THRESH 0.3f
#define MCAP 1024     // per-batch candidate list capacity (>= NN)
#define RCHUNK 192    // suppression-matrix rows per chunk
#define WMAX 16       // 64-bit words per keep row (1024/64)

// glist entry: 8 floats = {y1,x1,y2,x2,score,cls,orig_idx,pad}

// ---------------- Kernel A: one wave (64 lanes) per ROI ----------------
// Argmax over 81 classes via coalesced lane loads + shuffle reduce; lane 0
// decodes/clips the box and appends VALID candidates to a per-batch global
// list (device-scope atomic counter). Block 0 also zeroes d_out.
__global__ __launch_bounds__(256) void roi_kernel(
    const float* __restrict__ rois,      // B,N,4
    const float* __restrict__ probs,     // B,N,C
    const float* __restrict__ deltas,    // B,N,C,4
    const float* __restrict__ std_dev,   // 4
    int* __restrict__ gcnt,              // 32 counters (pre-zeroed)
    float* __restrict__ glist,           // B x MCAP x 8
    float* __restrict__ out)             // B,MAX_INST,6 (zeroed here)
{
  // zero the output slab (harness poisons d_out with 0xAA)
  if (blockIdx.x == 0) {
    float4* o4 = (float4*)out;
    for (int i = threadIdx.x; i < BB * MAX_INST * 6 / 4; i += 256)
      o4[i] = make_float4(0.f, 0.f, 0.f, 0.f);
  }

  int wg = blockIdx.x * 4 + (threadIdx.x >> 6);
  if (wg >= BB * NN) return;
  int lane = threadIdx.x & 63;

  const float* p = probs + (size_t)wg * CC;
  float v = p[lane];              // lanes 0..63 cover classes 0..63
  int   c = lane;
  if (lane + 64 < CC) {           // lanes 0..16 also cover classes 64..80
    float v2 = p[lane + 64];
    if (v2 > v) { v = v2; c = lane + 64; }   // lower class wins ties
  }
  // first-occurrence argmax: on ties keep smaller class index
  for (int off = 32; off; off >>= 1) {
    float vo = __shfl_down(v, off);
    int   co = __shfl_down(c, off);
    if (vo > v || (vo == v && co < c)) { v = vo; c = co; }
  }

  if (lane == 0 && c > 0 && v >= MIN_CONF) {
    float4 dd = *(const float4*)(deltas + ((size_t)wg * CC + c) * 4);
    float4 r4 = *(const float4*)(rois + (size_t)wg * 4);
    float dy = dd.x * std_dev[0], dx = dd.y * std_dev[1];
    float dh = dd.z * std_dev[2], dw = dd.w * std_dev[3];
    float h = r4.z - r4.x, w = r4.w - r4.y;
    float cy = r4.x + 0.5f * h + dy * h;
    float cx = r4.y + 0.5f * w + dx * w;
    h *= expf(dh); w *= expf(dw);
    float y1 = cy - 0.5f * h, x1 = cx - 0.5f * w;
    float y2 = y1 + h,        x2 = x1 + w;
    y1 = fminf(fmaxf(y1, 0.f), 1.f); x1 = fminf(fmaxf(x1, 0.f), 1.f);
    y2 = fminf(fmaxf(y2, 0.f), 1.f); x2 = fminf(fmaxf(x2, 0.f), 1.f);
    int b = wg / NN, n = wg - b * NN;
    int pos = atomicAdd(&gcnt[b], 1);          // device-scope
    float4* o = (float4*)(glist + ((size_t)b * MCAP + pos) * 8);
    o[0] = make_float4(y1, x1, y2, x2);
    o[1] = make_float4(v, (float)c, (float)n, 0.f);
  }
}

// ------------- Kernel B: one 256-thread block per batch — sort+NMS -------------
__global__ __launch_bounds__(256) void nms_kernel(
    const int* __restrict__ gcnt,
    const float* __restrict__ glist,
    float* __restrict__ out)         // B,MAX_INST,6
{
  const int b = blockIdx.x, t = threadIdx.x;

  __shared__ float cscore[MCAP];   // append-order scores
  __shared__ int   cidx[MCAP];     // append-order original indices
  __shared__ float sy1[MCAP], sx1[MCAP], sy2[MCAP], sx2[MCAP]; // sorted boxes
  __shared__ int   scls[MCAP];     // sorted classes
  __shared__ float sscr[MCAP];     // sorted scores
  __shared__ unsigned long long rows[RCHUNK][WMAX];
  __shared__ unsigned long long keepw[WMAX];

  const int M = gcnt[b];
  const int W = (M + 63) >> 6;
  const float* base = glist + (size_t)b * MCAP * 8;

  // append-order keys into LDS
  for (int e = t; e < M; e += 256) {
    const float4 s = ((const float4*)(base + (size_t)e * 8))[1];
    cscore[e] = s.x; cidx[e] = (int)s.z;
  }
  __syncthreads();

  // rank = stable-argsort position (score desc, orig idx asc); scatter sorted
  for (int e = t; e < M; e += 256) {
    const float4 a = ((const float4*)(base + (size_t)e * 8))[0];
    const float4 s = ((const float4*)(base + (size_t)e * 8))[1];
    float sc = s.x; int oi = (int)s.z;
    int r = 0;
    for (int j = 0; j < M; ++j) {
      float sj = cscore[j]; int ij = cidx[j];
      if (sj > sc || (sj == sc && ij < oi)) ++r;
    }
    sy1[r] = a.x; sx1[r] = a.y; sy2[r] = a.z; sx2[r] = a.w;
    scls[r] = (int)s.y; sscr[r] = sc;
  }
  if (t < WMAX) {
    unsigned long long kw = 0ULL;
    int nb = M - t * 64;
    if (nb > 0) kw = (nb >= 64) ? ~0ULL : ((1ULL << nb) - 1ULL);
    keepw[t] = kw;
  }
  __syncthreads();

  // chunked suppression matrix (ballot rows) + wave-serial keep propagation
  const int wv = t >> 6, lane = t & 63;
  for (int c0 = 0; c0 < M; c0 += RCHUNK) {
    int R = min(RCHUNK, M - c0);
    for (int task = wv; task < R * W; task += 4) {
      int i = c0 + task / W;
      int w = task % W;
      int j = w * 64 + lane;
      bool cond = false;
      float iy1 = sy1[i], ix1 = sx1[i], iy2 = sy2[i], ix2 = sx2[i];
      int ic = scls[i];
      if (j < M && j > i && scls[j] == ic) {
        float jy1 = sy1[j], jx1 = sx1[j], jy2 = sy2[j], jx2 = sx2[j];
        float ai = (iy2 - iy1) * (ix2 - ix1);
        float aj = (jy2 - jy1) * (jx2 - jx1);
        float iy = fmaxf(fminf(iy2, jy2) - fmaxf(iy1, jy1), 0.f);
        float ix = fmaxf(fminf(ix2, jx2) - fmaxf(ix1, jx1), 0.f);
        float inter = iy * ix;
        float uni = fmaxf(ai + aj - inter, 1e-8f);
        cond = (inter / uni) > NMS_THRESH;
      }
      unsigned long long word = __ballot(cond);
      if (lane == 0) rows[task / W][w] = word;
    }
    __syncthreads();
    if (t < 64) {
      unsigned long long kw = (t < W) ? keepw[t] : 0ULL;
      for (int i = c0; i < c0 + R; ++i) {
        unsigned long long kwi = __shfl((long long)kw, i >> 6); // uniform lane
        if ((kwi >> (i & 63)) & 1ULL) {
          if (t < W) kw &= ~rows[i - c0][t];
        }
      }
      if (t < W) keepw[t] = kw;
    }
    __syncthreads();
  }

  // slot = popcount of kept entries ahead; write kept rows
  for (int r = t; r < M; r += 256) {
    unsigned long long kwme = keepw[r >> 6];
    if ((kwme >> (r & 63)) & 1ULL) {
      int slot = 0;
      for (int w = 0; w < (r >> 6); ++w) slot += __popcll(keepw[w]);
      slot += __popcll(kwme & ((1ULL << (r & 63)) - 1ULL));
      if (slot < MAX_INST) {
        float* o = out + ((size_t)b * MAX_INST + slot) * 6;
        o[0] = sy1[r]; o[1] = sx1[r]; o[2] = sy2[r]; o[3] = sx2[r];
        o[4] = (float)scls[r]; o[5] = sscr[r];
      }
    }
  }
}

extern "C" void kernel_launch(void* const* d_in, const int* in_sizes, int n_in,
                              void* d_out, int out_size, void* d_ws, size_t ws_size,
                              hipStream_t stream) {
  const float* rois    = (const float*)d_in[0];
  const float* probs   = (const float*)d_in[1];
  const float* deltas  = (const float*)d_in[2];
  const float* std_dev = (const float*)d_in[3];
  float* out = (float*)d_out;

  int*   gcnt  = (int*)d_ws;                       // 32 ints (+pad to 128 B)
  float* glist = (float*)((char*)d_ws + 128);      // 32 x 1024 x 8 floats = 1 MB

  hipMemsetAsync(gcnt, 0, 128, stream);
  roi_kernel<<<(BB * NN + 3) / 4, 256, 0, stream>>>(rois, probs, deltas, std_dev,
                                                    gcnt, glist, out);
  nms_kernel<<<BB, 256, 0, stream>>>(gcnt, glist, out);
}